// Round 1
// 16347.786 us; speedup vs baseline: 2.0054x; 2.0054x over previous
//
#include <hip/hip_runtime.h>
#include <cstddef>

// Model constants
#define NLAYER 24
#define DMODEL 768
#define DINNER 1536
#define DSTATE 16
#define DTRANK 48
#define SEQL   1024
#define NB     2
#define ROWS   (NB*SEQL)            // 2048 rows per direction
#define XPN    (DTRANK + 2*DSTATE)  // 80

// Chunked scan parameters
#define NCHUNK 16
#define CLEN   64                   // SEQL / NCHUNK

__device__ __forceinline__ float sigm(float x){ return 1.0f/(1.0f + __expf(-x)); }

// ---------------------------------------------------------------------------
// Embedding gather. x layout: [dir][b][l][DMODEL]. bwd dir reads flipped ids.
// ---------------------------------------------------------------------------
__global__ __launch_bounds__(256) void embed_kernel(
    const int* __restrict__ ids,
    const float* __restrict__ ef, const float* __restrict__ eb,
    float* __restrict__ x)
{
  int row = blockIdx.x;                       // dir*2048 + b*1024 + l
  int dir = row >> 11, bl = row & 2047, b = bl >> 10, l = bl & 1023;
  int sl = dir ? (SEQL - 1 - l) : l;
  int tok = ids[b*SEQL + sl];
  const float* e = (dir ? eb : ef) + (size_t)tok * DMODEL;
  float* xr = x + (size_t)row * DMODEL;
  for (int c = threadIdx.x; c < DMODEL; c += 256) xr[c] = e[c];
}

// ---------------------------------------------------------------------------
// RMSNorm: one block (256 thr) per row of 768.
// ---------------------------------------------------------------------------
__global__ __launch_bounds__(256) void rmsnorm_kernel(
    const float* __restrict__ x,
    const float* __restrict__ wf, const float* __restrict__ wb,
    float* __restrict__ h)
{
  int row = blockIdx.x; int dir = row >> 11;
  const float* w  = dir ? wb : wf;            // pre-offset by layer on host
  const float* xr = x + (size_t)row * DMODEL;
  int t = threadIdx.x;
  float v0 = xr[t], v1 = xr[t+256], v2 = xr[t+512];
  float s = v0*v0 + v1*v1 + v2*v2;
  #pragma unroll
  for (int off = 32; off > 0; off >>= 1) s += __shfl_down(s, off);
  __shared__ float red[4];
  if ((t & 63) == 0) red[t >> 6] = s;
  __syncthreads();
  s = red[0] + red[1] + red[2] + red[3];
  float inv = rsqrtf(s * (1.0f/DMODEL) + 1e-5f);
  float* hr = h + (size_t)row * DMODEL;
  hr[t]     = v0 * inv * w[t];
  hr[t+256] = v1 * inv * w[t+256];
  hr[t+512] = v2 * inv * w[t+512];
}

// ---------------------------------------------------------------------------
// gemm128: C[M,N] = A[M,K] * W[N,K]^T.  BM=BN=128, BK=16, 256 thr, 8x8/thread.
// MODE 0: store C.  MODE 1: store C and also d_out slice (out_proj epilogue).
// blockIdx.z = direction (0 fwd, 1 bwd).
// ---------------------------------------------------------------------------
template<int MODE>
__global__ __launch_bounds__(256) void gemm128(
    const float* __restrict__ A, int lda,
    const float* __restrict__ Wf, const float* __restrict__ Wb,
    float* __restrict__ C, int ldc, int K,
    float* __restrict__ dout, int layer)
{
  int dir = blockIdx.z;
  const float* W = dir ? Wb : Wf;
  A += (size_t)dir * ROWS * lda;
  C += (size_t)dir * ROWS * ldc;
  int m0 = blockIdx.y * 128, n0 = blockIdx.x * 128;
  __shared__ alignas(16) float As[16][132];   // [k][m]
  __shared__ alignas(16) float Bs[16][132];   // [k][n]
  int t = threadIdx.x;
  int ty = t >> 4, tx = t & 15;
  float acc[8][8];
  #pragma unroll
  for (int i = 0; i < 8; ++i)
    #pragma unroll
    for (int j = 0; j < 8; ++j) acc[i][j] = 0.0f;

  for (int k0 = 0; k0 < K; k0 += 16) {
    #pragma unroll
    for (int j = 0; j < 2; ++j) {
      int idx = t + 256*j;
      int row = idx >> 2, kq = idx & 3;
      float4 av = *reinterpret_cast<const float4*>(A + (size_t)(m0+row)*lda + k0 + kq*4);
      As[kq*4+0][row] = av.x; As[kq*4+1][row] = av.y;
      As[kq*4+2][row] = av.z; As[kq*4+3][row] = av.w;
      float4 wv = *reinterpret_cast<const float4*>(W + (size_t)(n0+row)*K + k0 + kq*4);
      Bs[kq*4+0][row] = wv.x; Bs[kq*4+1][row] = wv.y;
      Bs[kq*4+2][row] = wv.z; Bs[kq*4+3][row] = wv.w;
    }
    __syncthreads();
    #pragma unroll
    for (int k = 0; k < 16; ++k) {
      float4 a0 = *reinterpret_cast<const float4*>(&As[k][ty*8]);
      float4 a1 = *reinterpret_cast<const float4*>(&As[k][ty*8+4]);
      float4 b0 = *reinterpret_cast<const float4*>(&Bs[k][tx*8]);
      float4 b1 = *reinterpret_cast<const float4*>(&Bs[k][tx*8+4]);
      float a[8] = {a0.x,a0.y,a0.z,a0.w,a1.x,a1.y,a1.z,a1.w};
      float b[8] = {b0.x,b0.y,b0.z,b0.w,b1.x,b1.y,b1.z,b1.w};
      #pragma unroll
      for (int i = 0; i < 8; ++i)
        #pragma unroll
        for (int j = 0; j < 8; ++j) acc[i][j] += a[i]*b[j];
    }
    __syncthreads();
  }

  #pragma unroll
  for (int i = 0; i < 8; ++i) {
    int m = m0 + ty*8 + i;
    float4 o0 = make_float4(acc[i][0],acc[i][1],acc[i][2],acc[i][3]);
    float4 o1 = make_float4(acc[i][4],acc[i][5],acc[i][6],acc[i][7]);
    float* cr = C + (size_t)m*ldc + n0 + tx*8;
    *reinterpret_cast<float4*>(cr)   = o0;
    *reinterpret_cast<float4*>(cr+4) = o1;
    if (MODE == 1) {
      int b = m >> 10, l = m & 1023;
      float* orr = dout + (((size_t)layer*NB + b)*SEQL + l)*(2*DMODEL) + dir*DMODEL + n0 + tx*8;
      *reinterpret_cast<float4*>(orr)   = o0;
      *reinterpret_cast<float4*>(orr+4) = o1;
    }
  }
}

// ---------------------------------------------------------------------------
// gemm64: C[M,N] = A[M,K] * W[N,K]^T (+ bias, softplus).  BM=BN=64, BK=16,
// 256 thr, 4x4/thread.  Handles N not multiple of 64 (x_proj N=80).
// MODE 0: plain.  MODE 1: softplus(v + bias[n]) (dt projection).
// ---------------------------------------------------------------------------
template<int MODE>
__global__ __launch_bounds__(256) void gemm64(
    const float* __restrict__ A, int lda,
    const float* __restrict__ Wf, const float* __restrict__ Wb,
    float* __restrict__ C, int ldc, int N, int K,
    const float* __restrict__ biasf, const float* __restrict__ biasb)
{
  int dir = blockIdx.z;
  const float* W    = dir ? Wb : Wf;
  const float* bias = dir ? biasb : biasf;
  A += (size_t)dir * ROWS * lda;
  C += (size_t)dir * ROWS * ldc;
  int m0 = blockIdx.y * 64, n0 = blockIdx.x * 64;
  __shared__ alignas(16) float As[16][68];
  __shared__ alignas(16) float Bs[16][68];
  int t = threadIdx.x;
  int ty = t >> 4, tx = t & 15;
  float acc[4][4];
  #pragma unroll
  for (int i = 0; i < 4; ++i)
    #pragma unroll
    for (int j = 0; j < 4; ++j) acc[i][j] = 0.0f;

  for (int k0 = 0; k0 < K; k0 += 16) {
    int row = t >> 2, kq = t & 3;
    float4 av = *reinterpret_cast<const float4*>(A + (size_t)(m0+row)*lda + k0 + kq*4);
    As[kq*4+0][row] = av.x; As[kq*4+1][row] = av.y;
    As[kq*4+2][row] = av.z; As[kq*4+3][row] = av.w;
    float4 wv = make_float4(0.f,0.f,0.f,0.f);
    if (n0 + row < N)
      wv = *reinterpret_cast<const float4*>(W + (size_t)(n0+row)*K + k0 + kq*4);
    Bs[kq*4+0][row] = wv.x; Bs[kq*4+1][row] = wv.y;
    Bs[kq*4+2][row] = wv.z; Bs[kq*4+3][row] = wv.w;
    __syncthreads();
    #pragma unroll
    for (int k = 0; k < 16; ++k) {
      float4 a4 = *reinterpret_cast<const float4*>(&As[k][ty*4]);
      float4 b4 = *reinterpret_cast<const float4*>(&Bs[k][tx*4]);
      float a[4] = {a4.x,a4.y,a4.z,a4.w};
      float b[4] = {b4.x,b4.y,b4.z,b4.w};
      #pragma unroll
      for (int i = 0; i < 4; ++i)
        #pragma unroll
        for (int j = 0; j < 4; ++j) acc[i][j] += a[i]*b[j];
    }
    __syncthreads();
  }

  #pragma unroll
  for (int i = 0; i < 4; ++i) {
    int m = m0 + ty*4 + i;
    #pragma unroll
    for (int j = 0; j < 4; ++j) {
      int n = n0 + tx*4 + j;
      if (n < N) {
        float v = acc[i][j];
        if (MODE == 1) {                       // softplus(v + dt_b[n])
          v += bias[n];
          v = (v > 15.0f) ? v : log1pf(__expf(v));
        }
        C[(size_t)m*ldc + n] = v;
      }
    }
  }
}

// ---------------------------------------------------------------------------
// Causal depthwise conv (K=4) + SiLU.  Reads xs = xz[:, 0:DINNER].
// grid: (DINNER/256, ROWS, 2)
// ---------------------------------------------------------------------------
__global__ __launch_bounds__(256) void conv_silu_kernel(
    const float* __restrict__ xz,
    const float* __restrict__ cwf, const float* __restrict__ cwb,
    const float* __restrict__ cbf, const float* __restrict__ cbb,
    float* __restrict__ xc)
{
  int d = blockIdx.x*256 + threadIdx.x;
  int dir = blockIdx.z;
  int r = dir * ROWS + blockIdx.y;            // global row
  int l = blockIdx.y & 1023;
  const float* cw = (dir ? cwb : cwf) + (size_t)d*4;  // pre-offset by layer
  float acc = (dir ? cbb : cbf)[d];
  #pragma unroll
  for (int k = 0; k < 4; ++k) {
    int ll = l + k - 3;
    if (ll >= 0) acc += xz[(size_t)(r + k - 3)*(2*DINNER) + d] * cw[k];
  }
  xc[(size_t)r*DINNER + d] = acc * sigm(acc);
}

// ---------------------------------------------------------------------------
// Chunked selective scan (exact two-pass linear-recurrence split).
// Rows for (dirb = dir*NB+b) live at [dirb*1024 + l].
//
// pass1: per (dirb, chunk, d): scan CLEN steps from h=0, emit
//        P[n] = prod dA  and  hloc[n]  into [dirb][chunk][n][DINNER].
// combine: per (dirb, n, d): serial over chunks -> entry state h0 per chunk.
// pass2: per (dirb, chunk, d): rerun chunk from h0, full gating epilogue -> y.
// ---------------------------------------------------------------------------
__global__ __launch_bounds__(128) void scan_pass1(
    const float* __restrict__ delta, const float* __restrict__ xc,
    const float* __restrict__ dbl,
    const float* __restrict__ Af, const float* __restrict__ Ab,
    float* __restrict__ Pbuf, float* __restrict__ Hbuf)
{
  int dirb = blockIdx.z;
  int dir  = dirb >> 1;
  int c    = blockIdx.y;
  int d    = blockIdx.x*128 + threadIdx.x;
  const float* Alog = (dir ? Ab : Af) + (size_t)d * DSTATE;  // pre-offset by layer
  float An[DSTATE];
  #pragma unroll
  for (int n = 0; n < DSTATE; ++n) An[n] = -__expf(Alog[n]);

  size_t rb = (size_t)dirb * SEQL + (size_t)c * CLEN;        // row base
  __shared__ float Bs[CLEN][DSTATE];
  for (int i = threadIdx.x; i < CLEN*DSTATE; i += 128) {
    int tt = i >> 4, q = i & 15;
    Bs[tt][q] = dbl[(rb+tt)*XPN + DTRANK + q];
  }
  __syncthreads();

  float h[DSTATE], Pp[DSTATE];
  #pragma unroll
  for (int n = 0; n < DSTATE; ++n) { h[n] = 0.0f; Pp[n] = 1.0f; }

  size_t idx = rb * DINNER + d;
  float dv = delta[idx], xv = xc[idx];                       // step-0 prefetch
  for (int tt = 0; tt < CLEN; ++tt) {
    float dvc = dv, xvc = xv;
    if (tt + 1 < CLEN) {                                     // 1-step reg prefetch
      size_t nx = idx + (size_t)(tt+1)*DINNER;
      dv = delta[nx]; xv = xc[nx];
    }
    float dx = dvc * xvc;
    #pragma unroll
    for (int n = 0; n < DSTATE; ++n) {
      float dA = __expf(dvc * An[n]);
      h[n]  = h[n]*dA + dx*Bs[tt][n];
      Pp[n] *= dA;
    }
  }
  size_t o = (((size_t)dirb*NCHUNK + c)*DSTATE)*DINNER + d;
  #pragma unroll
  for (int n = 0; n < DSTATE; ++n) {
    Pbuf[o + (size_t)n*DINNER] = Pp[n];
    Hbuf[o + (size_t)n*DINNER] = h[n];
  }
}

__global__ __launch_bounds__(256) void scan_combine(
    const float* __restrict__ Pbuf, const float* __restrict__ Hbuf,
    float* __restrict__ H0)
{
  int gid = blockIdx.x*256 + threadIdx.x;    // 4 * 16 * 1536 threads
  int d   = gid % DINNER;
  int rn  = gid / DINNER;
  int n = rn & 15, dirb = rn >> 4;
  float h = 0.0f;
  for (int c = 0; c < NCHUNK; ++c) {
    size_t o = (((size_t)dirb*NCHUNK + c)*DSTATE + n)*DINNER + d;
    H0[o] = h;                                // state ENTERING chunk c
    h = h*Pbuf[o] + Hbuf[o];
  }
}

__global__ __launch_bounds__(128) void scan_pass2(
    const float* __restrict__ delta, const float* __restrict__ xc,
    const float* __restrict__ dbl,   const float* __restrict__ xz,
    const float* __restrict__ H0,
    const float* __restrict__ Af, const float* __restrict__ Ab,
    const float* __restrict__ Df, const float* __restrict__ Db,
    float* __restrict__ y)
{
  int dirb = blockIdx.z;
  int dir  = dirb >> 1;
  int c    = blockIdx.y;
  int d    = blockIdx.x*128 + threadIdx.x;
  const float* Alog = (dir ? Ab : Af) + (size_t)d * DSTATE;
  float An[DSTATE];
  #pragma unroll
  for (int n = 0; n < DSTATE; ++n) An[n] = -__expf(Alog[n]);
  float Dv = (dir ? Db : Df)[d];

  size_t rb = (size_t)dirb * SEQL + (size_t)c * CLEN;
  __shared__ float BCs[CLEN][32];             // [tt][0:16]=B, [16:32]=C
  for (int i = threadIdx.x; i < CLEN*32; i += 128) {
    int tt = i >> 5, q = i & 31;
    BCs[tt][q] = dbl[(rb+tt)*XPN + DTRANK + q];
  }
  __syncthreads();

  float h[DSTATE];
  size_t ho = (((size_t)dirb*NCHUNK + c)*DSTATE)*DINNER + d;
  #pragma unroll
  for (int n = 0; n < DSTATE; ++n) h[n] = H0[ho + (size_t)n*DINNER];

  size_t idx = rb * DINNER + d;
  float dv = delta[idx], xv = xc[idx];
  float zv = xz[rb*(size_t)(2*DINNER) + DINNER + d];
  for (int tt = 0; tt < CLEN; ++tt) {
    float dvc = dv, xvc = xv, zvc = zv;
    if (tt + 1 < CLEN) {
      size_t nx = idx + (size_t)(tt+1)*DINNER;
      dv = delta[nx]; xv = xc[nx];
      zv = xz[(rb+tt+1)*(size_t)(2*DINNER) + DINNER + d];
    }
    float dx = dvc * xvc;
    float accv = 0.0f;
    #pragma unroll
    for (int n = 0; n < DSTATE; ++n) {
      float dA = __expf(dvc * An[n]);
      h[n] = h[n]*dA + dx*BCs[tt][n];
      accv += h[n]*BCs[tt][DSTATE+n];
    }
    y[idx + (size_t)tt*DINNER] = (accv + xvc*Dv) * (zvc * sigm(zvc));
  }
}

// ---------------------------------------------------------------------------
// Host launcher: embed, then 24 layers x {rmsnorm, in_proj, conv, x_proj,
// dt_proj, scan(3 kernels), out_proj}.  Both directions fused per launch.
// ---------------------------------------------------------------------------
extern "C" void kernel_launch(void* const* d_in, const int* in_sizes, int n_in,
                              void* d_out, int out_size, void* d_ws, size_t ws_size,
                              hipStream_t stream)
{
  const int* ids = (const int*)d_in[0];
  // param index j: 0 embed, 1 norm_w, 2 in_proj, 3 conv_w, 4 conv_b,
  //                5 x_proj, 6 dt_w, 7 dt_b, 8 A_log, 9 Dp, 10 out_proj
  const float* P[2][11];
  for (int dir = 0; dir < 2; ++dir)
    for (int j = 0; j < 11; ++j)
      P[dir][j] = (const float*)d_in[1 + dir*11 + j];

  float* ws   = (float*)d_ws;
  float* x    = ws;                                   // [2][2048][768]
  float* h    = x    + (size_t)2*ROWS*DMODEL;         // [2][2048][768]
  float* xz   = h    + (size_t)2*ROWS*DMODEL;         // [2][2048][3072]
  float* xcb  = xz   + (size_t)2*ROWS*2*DINNER;       // [2][2048][1536]
  float* dblb = xcb  + (size_t)2*ROWS*DINNER;         // [2][2048][80]
  float* dlt  = dblb + (size_t)2*ROWS*XPN;            // [2][2048][1536]
  float* yb   = dlt  + (size_t)2*ROWS*DINNER;         // [2][2048][1536]
  float* h0b  = yb   + (size_t)2*ROWS*DINNER;         // [4][NC][16][1536] (new, 6.3MB)
  float* out  = (float*)d_out;                        // [24][2][1024][1536]

  // P/hloc chunk summaries reuse the h buffer (dead between in_proj and next
  // layer's rmsnorm).  Each is 4*NCHUNK*DSTATE*DINNER = 1.57M floats; the two
  // together exactly fill h's 2*ROWS*DMODEL = 3.15M floats.
  float* Pb = h;
  float* Hb = h + (size_t)4*NCHUNK*DSTATE*DINNER;

  embed_kernel<<<dim3(2*ROWS), 256, 0, stream>>>(ids, P[0][0], P[1][0], x);

  for (int layer = 0; layer < NLAYER; ++layer) {
    rmsnorm_kernel<<<dim3(2*ROWS), 256, 0, stream>>>(
        x, P[0][1] + (size_t)layer*DMODEL, P[1][1] + (size_t)layer*DMODEL, h);

    // in_proj: [2048,768] x [3072,768]^T -> xz [2048,3072]
    gemm128<0><<<dim3(2*DINNER/128, ROWS/128, 2), 256, 0, stream>>>(
        h, DMODEL,
        P[0][2] + (size_t)layer*2*DINNER*DMODEL,
        P[1][2] + (size_t)layer*2*DINNER*DMODEL,
        xz, 2*DINNER, DMODEL, nullptr, 0);

    conv_silu_kernel<<<dim3(DINNER/256, ROWS, 2), 256, 0, stream>>>(
        xz,
        P[0][3] + (size_t)layer*DINNER*4, P[1][3] + (size_t)layer*DINNER*4,
        P[0][4] + (size_t)layer*DINNER,   P[1][4] + (size_t)layer*DINNER,
        xcb);

    // x_proj: [2048,1536] x [80,1536]^T -> dbl [2048,80]
    gemm64<0><<<dim3((XPN+63)/64, ROWS/64, 2), 256, 0, stream>>>(
        xcb, DINNER,
        P[0][5] + (size_t)layer*XPN*DINNER,
        P[1][5] + (size_t)layer*XPN*DINNER,
        dblb, XPN, XPN, DINNER, nullptr, nullptr);

    // delta = softplus(dt @ dt_w^T + dt_b): [2048,48] x [1536,48]^T -> [2048,1536]
    gemm64<1><<<dim3(DINNER/64, ROWS/64, 2), 256, 0, stream>>>(
        dblb, XPN,
        P[0][6] + (size_t)layer*DINNER*DTRANK,
        P[1][6] + (size_t)layer*DINNER*DTRANK,
        dlt, DINNER, DINNER, DTRANK,
        P[0][7] + (size_t)layer*DINNER, P[1][7] + (size_t)layer*DINNER);

    // chunked selective scan: 768-block passes replace the 24-block serial scan
    scan_pass1<<<dim3(DINNER/128, NCHUNK, 4), 128, 0, stream>>>(
        dlt, xcb, dblb,
        P[0][8] + (size_t)layer*DINNER*DSTATE, P[1][8] + (size_t)layer*DINNER*DSTATE,
        Pb, Hb);

    scan_combine<<<dim3(4*DSTATE*DINNER/256), 256, 0, stream>>>(Pb, Hb, h0b);

    scan_pass2<<<dim3(DINNER/128, NCHUNK, 4), 128, 0, stream>>>(
        dlt, xcb, dblb, xz, h0b,
        P[0][8] + (size_t)layer*DINNER*DSTATE, P[1][8] + (size_t)layer*DINNER*DSTATE,
        P[0][9] + (size_t)layer*DINNER,        P[1][9] + (size_t)layer*DINNER,
        yb);

    // out_proj: [2048,1536] x [768,1536]^T -> x (next layer input) + d_out slice
    gemm128<1><<<dim3(DMODEL/128, ROWS/128, 2), 256, 0, stream>>>(
        yb, DINNER,
        P[0][10] + (size_t)layer*DMODEL*DINNER,
        P[1][10] + (size_t)layer*DMODEL*DINNER,
        x, DMODEL, DINNER, out, layer);
  }
}